// Round 2
// baseline (609.858 us; speedup 1.0000x reference)
//
#include <hip/hip_runtime.h>

// ---------------------------------------------------------------------------
// LlamaAttention fwd: B=1, S=2048, HID=4096, NH=32, NKV=8, HD=128, GQA x4.
// fp32 in/out; bf16 MFMA internally.
// R5: fix GEMM LDS swizzle 1-bit -> 3-bit (G4 recipe: byte ^= (row&7)<<4).
// Row stride of the LDS tiles is 128B, so bank slot = column byte; 3 XOR bits
// spread 8 consecutive rows over all 8 16B slots (2-way residual is free).
// Phase-1 k-slice offset (+64B = bit6) must go THROUGH the XOR, so phase-0
// and phase-1 read bases are computed separately. Write side stays linear
// (global_load_lds) with the involution pre-applied to the global source col.
// ---------------------------------------------------------------------------

typedef __bf16 bf16_t;
typedef bf16_t bf16x8_t __attribute__((ext_vector_type(8)));
typedef float f32x4_t __attribute__((ext_vector_type(4)));

#define S_LEN 2048
#define HID 4096
#define NH 32
#define NKV 8
#define HD 128
#define KV_DIM 1024
#define QKV_DIM 6144                 // 4096 q | 1024 k | 1024 v
#define SCALE 0.08838834764831845f   // 1/sqrt(128)

// -------- persistent device scratch ----------------------------------------
__device__ __align__(16) bf16_t g_hsb[(size_t)S_LEN * HID];
__device__ __align__(16) bf16_t g_wqkvT[(size_t)QKV_DIM * HID];  // [n][k]
__device__ __align__(16) bf16_t g_woT[(size_t)HID * HID];        // [n][k]
__device__ __align__(16) bf16_t g_qkv[(size_t)S_LEN * QKV_DIM];  // post-RoPE
__device__ __align__(16) bf16_t g_vT[(size_t)NKV * HD * S_LEN];  // [kvh][d][s]
__device__ __align__(16) bf16_t g_ao[(size_t)S_LEN * HID];       // attn out

// async global->LDS, 16B per lane; LDS dest is wave-uniform base + lane*16
__device__ __forceinline__ void gl_lds16(const bf16_t* g, bf16_t* l) {
  __builtin_amdgcn_global_load_lds(
      (const __attribute__((address_space(1))) void*)g,
      (__attribute__((address_space(3))) void*)l, 16, 0, 0);
}

// ---------------------------------------------------------------------------
__global__ __launch_bounds__(256) void cast_f32_bf16(
    const float* __restrict__ in, bf16_t* __restrict__ out)
{
  size_t i = ((size_t)blockIdx.x * 256 + threadIdx.x) * 8;
  float4 a = *(const float4*)(in + i);
  float4 b = *(const float4*)(in + i + 4);
  bf16x8_t r;
  r[0] = (bf16_t)a.x; r[1] = (bf16_t)a.y; r[2] = (bf16_t)a.z; r[3] = (bf16_t)a.w;
  r[4] = (bf16_t)b.x; r[5] = (bf16_t)b.y; r[6] = (bf16_t)b.z; r[7] = (bf16_t)b.w;
  *(bf16x8_t*)(out + i) = r;
}

// ---------------------------------------------------------------------------
// Transpose+cast: in fp32 [R][C] stride is -> out bf16 [C][R] stride os.
// ---------------------------------------------------------------------------
__global__ __launch_bounds__(256) void transpose_f32_bf16(
    const float* __restrict__ in, bf16_t* __restrict__ out, int is, int os)
{
  __shared__ __align__(16) bf16_t T[64 * 72];
  int r0 = blockIdx.x * 64, c0 = blockIdx.y * 64;
  int t = threadIdx.x;
#pragma unroll
  for (int it = 0; it < 2; ++it) {
    int idx = t + it * 256;
    int r = idx >> 3, c8 = (idx & 7) * 8;
    const float* p = in + (size_t)(r0 + r) * is + c0 + c8;
    float4 a = *(const float4*)p;
    float4 b = *(const float4*)(p + 4);
    bf16x8_t x;
    x[0] = (bf16_t)a.x; x[1] = (bf16_t)a.y; x[2] = (bf16_t)a.z; x[3] = (bf16_t)a.w;
    x[4] = (bf16_t)b.x; x[5] = (bf16_t)b.y; x[6] = (bf16_t)b.z; x[7] = (bf16_t)b.w;
    *(bf16x8_t*)(T + r * 72 + c8) = x;
  }
  __syncthreads();
#pragma unroll
  for (int it = 0; it < 2; ++it) {
    int idx = t + it * 256;
    int c = idx >> 3, r8 = (idx & 7) * 8;
    bf16x8_t x;
#pragma unroll
    for (int i = 0; i < 8; ++i) x[i] = T[(r8 + i) * 72 + c];
    *(bf16x8_t*)(out + (size_t)(c0 + c) * os + r0 + r8) = x;
  }
}

// ---------------------------------------------------------------------------
// bf16 batched transpose (V -> V^T per kv head).
// ---------------------------------------------------------------------------
__global__ __launch_bounds__(256) void transpose_bf16(
    const bf16_t* __restrict__ in, bf16_t* __restrict__ out,
    int is, int os, int in_b, int out_b)
{
  __shared__ __align__(16) bf16_t T[64 * 72];
  const bf16_t* inp = in + (size_t)blockIdx.z * in_b;
  bf16_t* outp = out + (size_t)blockIdx.z * out_b;
  int r0 = blockIdx.x * 64, c0 = blockIdx.y * 64;
  int t = threadIdx.x;
#pragma unroll
  for (int it = 0; it < 2; ++it) {
    int idx = t + it * 256;
    int r = idx >> 3, c8 = (idx & 7) * 8;
    *(bf16x8_t*)(T + r * 72 + c8) =
        *(const bf16x8_t*)(inp + (size_t)(r0 + r) * is + c0 + c8);
  }
  __syncthreads();
#pragma unroll
  for (int it = 0; it < 2; ++it) {
    int idx = t + it * 256;
    int c = idx >> 3, r8 = (idx & 7) * 8;
    bf16x8_t x;
#pragma unroll
    for (int i = 0; i < 8; ++i) x[i] = T[(r8 + i) * 72 + c];
    *(bf16x8_t*)(outp + (size_t)(c0 + c) * os + r0 + r8) = x;
  }
}

// ---------------------------------------------------------------------------
// Phased counted-vmcnt GEMM: C[M,N] = A[M,K] @ Bt[N,K]^T.
// BM=128, BN=256, BK=64. 512 threads = 8 waves (2M x 4N), each wave a 64x64
// output quadrant (4x4 16x16x32 MFMA frags). Triple-buffered LDS ring.
// 3-bit XOR swizzle: LDS[row][colb] holds global[row][colb ^ ((row&7)<<4)].
// ---------------------------------------------------------------------------
template <typename CT>
__global__ __launch_bounds__(512, 2) void gemm8p(
    const bf16_t* __restrict__ A, const bf16_t* __restrict__ Bt,
    CT* __restrict__ C, int K, int N)
{
  constexpr int BM = 128, BN = 256;
  constexpr int BUFE = (BM + BN) * 64;            // elements per ring buffer
  __shared__ __align__(16) bf16_t lds[3 * BUFE];  // 144 KiB
  const int t = threadIdx.x;
  const int wid = t >> 6, lane = t & 63;
  const int ln = lane & 15, lq = lane >> 4;
  const int wm = wid >> 2, wn = wid & 3;          // 2 x 4 wave grid
  const int m0 = blockIdx.x * BM, n0 = blockIdx.y * BN;

  // ---- read-side swizzle: column byte ^= ((row&7)<<4); row&7 == ln&7.
  // Phase k-slice offset (kk*64, bit6) must be inside the XOR -> two bases.
  const int lane_xor = (ln & 7) << 4;
  const int col0 = (lq * 16) ^ lane_xor;          // k-slice 0 column byte
  const int col1 = (64 + lq * 16) ^ lane_xor;     // k-slice 1 column byte
  const int arow = (wm * 64 + ln) * 128;          // frag row base (bytes)
  const int brow = (wn * 64 + ln) * 128;
  const int abase0 = arow + col0, abase1 = arow + col1;
  const int bbase0 = brow + col0, bbase1 = brow + col1;

  // ---- staging: thread stages 16B of row srow at slot (t&7). LDS dest is
  // linear (wave-uniform base + lane*16); global source column pre-swizzled
  // with the same involution so swizzled reads see logical data.
  const int srow = t >> 3;                                        // 0..63
  const int scol = ((((t & 7) * 16) ^ ((srow & 7) << 4)) >> 1);   // elements
  const bf16_t* Ag0 = A + (size_t)(m0 + srow) * K + scol;
  const bf16_t* Ag1 = Ag0 + (size_t)64 * K;
  const bf16_t* Bg0 = Bt + (size_t)(n0 + srow) * K + scol;
  const bf16_t* Bg1 = Bg0 + (size_t)64 * K;
  const bf16_t* Bg2 = Bg0 + (size_t)128 * K;
  const bf16_t* Bg3 = Bg0 + (size_t)192 * K;
  const int swb = wid * 512;      // wave-uniform LDS staging offset (elements)

  // ---- prologue: stage K-tiles 0 and 1 (6 loads each; never drain to 0)
  {
    bf16_t* Lb = lds + swb;
    gl_lds16(Ag0, Lb);            gl_lds16(Ag1, Lb + 4096);
    gl_lds16(Bg0, Lb + 8192);     gl_lds16(Bg1, Lb + 12288);
    gl_lds16(Bg2, Lb + 16384);    gl_lds16(Bg3, Lb + 20480);
    Lb = lds + BUFE + swb;
    gl_lds16(Ag0 + 64, Lb);         gl_lds16(Ag1 + 64, Lb + 4096);
    gl_lds16(Bg0 + 64, Lb + 8192);  gl_lds16(Bg1 + 64, Lb + 12288);
    gl_lds16(Bg2 + 64, Lb + 16384); gl_lds16(Bg3 + 64, Lb + 20480);
  }
  asm volatile("s_waitcnt vmcnt(6)" ::: "memory");   // tile 0 resident
  __builtin_amdgcn_sched_barrier(0);
  __builtin_amdgcn_s_barrier();

  f32x4_t acc[4][4] = {};
  const int NT = K >> 6;
  for (int tt = 0; tt < NT; ++tt) {
    const char* Rb = (const char*)(lds + (tt % 3) * BUFE);
    const char* Bb = Rb + 16384;                    // B region (BM*64*2 bytes)
    bf16_t* Ls = lds + ((tt + 2) % 3) * BUFE + swb; // stage target: tile t+2
    const int k2 = (tt + 2) << 6;
    const bool stg = (tt + 2) < NT;
    bf16x8_t af[4], bfr[4];

    // ================= phase 0: k-slice 0 =================
#pragma unroll
    for (int mi = 0; mi < 4; ++mi)
      af[mi] = *(const bf16x8_t*)(Rb + abase0 + mi * 2048);
#pragma unroll
    for (int ni = 0; ni < 4; ++ni)
      bfr[ni] = *(const bf16x8_t*)(Bb + bbase0 + ni * 2048);
    if (stg) {                                      // first 3 of 6 loads
      gl_lds16(Ag0 + k2, Ls);
      gl_lds16(Ag1 + k2, Ls + 4096);
      gl_lds16(Bg0 + k2, Ls + 8192);
    }
    __builtin_amdgcn_s_barrier();
    __builtin_amdgcn_s_setprio(1);
#pragma unroll
    for (int mi = 0; mi < 4; ++mi)
#pragma unroll
      for (int ni = 0; ni < 4; ++ni)
        acc[mi][ni] = __builtin_amdgcn_mfma_f32_16x16x32_bf16(
            af[mi], bfr[ni], acc[mi][ni], 0, 0, 0);
    __builtin_amdgcn_s_setprio(0);
    __builtin_amdgcn_s_barrier();

    // ================= phase 1: k-slice 1 =================
#pragma unroll
    for (int mi = 0; mi < 4; ++mi)
      af[mi] = *(const bf16x8_t*)(Rb + abase1 + mi * 2048);
#pragma unroll
    for (int ni = 0; ni < 4; ++ni)
      bfr[ni] = *(const bf16x8_t*)(Bb + bbase1 + ni * 2048);
    if (stg) {                                      // last 3 of 6 loads
      gl_lds16(Bg1 + k2, Ls + 12288);
      gl_lds16(Bg2 + k2, Ls + 16384);
      gl_lds16(Bg3 + k2, Ls + 20480);
    }
    __builtin_amdgcn_s_barrier();
    __builtin_amdgcn_s_setprio(1);
#pragma unroll
    for (int mi = 0; mi < 4; ++mi)
#pragma unroll
      for (int ni = 0; ni < 4; ++ni)
        acc[mi][ni] = __builtin_amdgcn_mfma_f32_16x16x32_bf16(
            af[mi], bfr[ni], acc[mi][ni], 0, 0, 0);
    __builtin_amdgcn_s_setprio(0);

    // -------- tile end: counted drain (tile t+1 ready; t+2 stays in flight)
    if (tt + 2 < NT) {
      asm volatile("s_waitcnt vmcnt(6)" ::: "memory");
    } else {
      asm volatile("s_waitcnt vmcnt(0)" ::: "memory");
    }
    __builtin_amdgcn_sched_barrier(0);
    __builtin_amdgcn_s_barrier();
  }

  // ---- epilogue (proven C/D mapping: col=ln, row=lq*4+r)
#pragma unroll
  for (int mi = 0; mi < 4; ++mi)
#pragma unroll
    for (int ni = 0; ni < 4; ++ni)
#pragma unroll
      for (int r = 0; r < 4; ++r)
        C[(size_t)(m0 + wm * 64 + mi * 16 + lq * 4 + r) * N
          + n0 + wn * 64 + ni * 16 + ln] = (CT)acc[mi][ni][r];
}

// ---------------------------------------------------------------------------
// RoPE in-place on fused qkv layout [s][6144]; cos/sin fp32 [S][128].
// ---------------------------------------------------------------------------
__global__ __launch_bounds__(256) void rope_kernel(
    bf16_t* __restrict__ qkv, const float* __restrict__ cs,
    const float* __restrict__ sn)
{
  int idx = blockIdx.x * 256 + threadIdx.x;   // S*(NH+NKV)*64 threads exact
  int d = idx & 63;
  int h = (idx >> 6) % (NH + NKV);
  int s = idx / (64 * (NH + NKV));
  float c = cs[s * HD + d], si = sn[s * HD + d];
  bf16_t* base = qkv + (size_t)s * QKV_DIM +
                 ((h < NH) ? h * HD : HID + (h - NH) * HD);
  float x1 = (float)base[d], x2 = (float)base[d + 64];
  base[d]      = (bf16_t)(x1 * c - x2 * si);
  base[d + 64] = (bf16_t)(x2 * c + x1 * si);
}

// ---------------------------------------------------------------------------
// Flash attention, causal, GQA. BK=64 k-tile, 64 q-rows/block (16/wave).
// Longest-first dispatch: qb = 31 - bid/32, head = bid%32.
// ---------------------------------------------------------------------------
__global__ __launch_bounds__(256) void attn_kernel(
    const bf16_t* __restrict__ QKV, const bf16_t* __restrict__ VT,
    bf16_t* __restrict__ O)
{
  __shared__ __align__(16) bf16_t Ks[64 * 136];    // [kpos][d], pad 128->136
  __shared__ __align__(16) bf16_t Vs[128 * 72];    // [d][kpos], pad 64->72
  __shared__ __align__(16) bf16_t Ps[4 * 16 * 72]; // per-wave [16 q][64 k]
  int t = threadIdx.x, wave = t >> 6, lane = t & 63;
  int ln = lane & 15, lq = lane >> 4;
  int bid = blockIdx.x;
  int qb = (S_LEN / 64 - 1) - (bid >> 5);
  int head = bid & 31, kvh = head >> 2;
  int q0 = qb * 64;
  int qr = q0 + wave * 16 + ln;

  bf16x8_t qf[4];
#pragma unroll
  for (int kk = 0; kk < 4; ++kk)
    qf[kk] = *(const bf16x8_t*)(QKV + (size_t)qr * QKV_DIM + head * HD +
                                kk * 32 + lq * 8);

  f32x4_t oa[8] = {};
  float m_r[4] = {-1e30f, -1e30f, -1e30f, -1e30f};
  float l_r[4] = {0.f, 0.f, 0.f, 0.f};

  int krow = t >> 4, kdc = (t & 15) * 8;   // Ks staging: 16 rows/pass
  int vrow = t >> 3, vkc = (t & 7) * 8;    // Vs staging: 32 rows/pass
  const bf16_t* Kg = QKV + HID + (size_t)kvh * HD;
  const bf16_t* Vg = VT + (size_t)kvh * HD * S_LEN;

  for (int kt = 0; kt <= qb; ++kt) {
    int kb = kt * 64;
    __syncthreads();
#pragma unroll
    for (int p = 0; p < 4; ++p) {
      int r_ = p * 16 + krow;
      *(bf16x8_t*)(Ks + r_ * 136 + kdc) =
          *(const bf16x8_t*)(Kg + (size_t)(kb + r_) * QKV_DIM + kdc);
      int d_ = p * 32 + vrow;
      *(bf16x8_t*)(Vs + d_ * 72 + vkc) =
          *(const bf16x8_t*)(Vg + (size_t)d_ * S_LEN + kb + vkc);
    }
    __syncthreads();

    // S = Q @ K^T : 4 col-tiles x 4 k-chunks
    f32x4_t sv[4] = {};
#pragma unroll
    for (int nt = 0; nt < 4; ++nt)
#pragma unroll
      for (int kk = 0; kk < 4; ++kk) {
        bf16x8_t kf = *(const bf16x8_t*)(Ks + (nt * 16 + ln) * 136 +
                                         kk * 32 + lq * 8);
        sv[nt] = __builtin_amdgcn_mfma_f32_16x16x32_bf16(qf[kk], kf, sv[nt],
                                                         0, 0, 0);
      }

    float p_[4][4];                        // [nt][r]
    if (kt == qb) {                        // diagonal tile: mask (uniform br.)
#pragma unroll
      for (int nt = 0; nt < 4; ++nt)
#pragma unroll
        for (int r = 0; r < 4; ++r) {
          int rq = wave * 16 + lq * 4 + r;
          p_[nt][r] = (nt * 16 + ln <= rq) ? sv[nt][r] * SCALE : -1e30f;
        }
    } else {
#pragma unroll
      for (int nt = 0; nt < 4; ++nt)
#pragma unroll
        for (int r = 0; r < 4; ++r) p_[nt][r] = sv[nt][r] * SCALE;
    }

    float mx[4];
#pragma unroll
    for (int r = 0; r < 4; ++r)
      mx[r] = fmaxf(fmaxf(p_[0][r], p_[1][r]), fmaxf(p_[2][r], p_[3][r]));
#pragma unroll
    for (int off = 8; off >= 1; off >>= 1)
#pragma unroll
      for (int r = 0; r < 4; ++r) mx[r] = fmaxf(mx[r], __shfl_xor(mx[r], off, 64));

    float al[4], rs[4];
#pragma unroll
    for (int r = 0; r < 4; ++r) {
      float mn = fmaxf(m_r[r], mx[r]);
      al[r] = __expf(m_r[r] - mn);
      m_r[r] = mn;
      rs[r] = 0.f;
#pragma unroll
      for (int nt = 0; nt < 4; ++nt) {
        p_[nt][r] = __expf(p_[nt][r] - mn);
        rs[r] += p_[nt][r];
      }
    }
#pragma unroll
    for (int off = 8; off >= 1; off >>= 1)
#pragma unroll
      for (int r = 0; r < 4; ++r) rs[r] += __shfl_xor(rs[r], off, 64);
#pragma unroll
    for (int r = 0; r < 4; ++r) l_r[r] = l_r[r] * al[r] + rs[r];
#pragma unroll
    for (int dt = 0; dt < 8; ++dt)
#pragma unroll
      for (int r = 0; r < 4; ++r) oa[dt][r] *= al[r];

    // P: C/D layout -> per-wave LDS slice -> A-operand layout (no barrier)
    bf16_t* myP = Ps + wave * 16 * 72;
#pragma unroll
    for (int nt = 0; nt < 4; ++nt)
#pragma unroll
      for (int r = 0; r < 4; ++r)
        myP[(lq * 4 + r) * 72 + nt * 16 + ln] = (bf16_t)p_[nt][r];
    bf16x8_t pf0 = *(const bf16x8_t*)(myP + ln * 72 + lq * 8);
    bf16x8_t pf1 = *(const bf16x8_t*)(myP + ln * 72 + 32 + lq * 8);
#pragma unroll
    for (int dt = 0; dt < 8; ++dt) {
      bf16x8_t v0 = *(const bf16x8_t*)(Vs + (dt * 16 + ln) * 72 + lq * 8);
      bf16x8_t v1 = *(const bf16x8_t*)(Vs + (dt * 16 + ln) * 72 + 32 + lq * 8);
      oa[dt] = __builtin_amdgcn_mfma_f32_16x16x32_bf16(pf0, v0, oa[dt], 0, 0, 0);
      oa[dt] = __builtin_amdgcn_mfma_f32_16x16x32_bf16(pf1, v1, oa[dt], 0, 0, 0);
    }
  }

#pragma unroll
  for (int dt = 0; dt < 8; ++dt)
#pragma unroll
    for (int r = 0; r < 4; ++r) {
      int row = q0 + wave * 16 + lq * 4 + r;
      O[(size_t)row * HID + head * HD + dt * 16 + ln] =
          (bf16_t)(oa[dt][r] / l_r[r]);
    }
}

// ---------------------------------------------------------------------------
extern "C" void kernel_launch(void* const* d_in, const int* in_sizes, int n_in,
                              void* d_out, int out_size, void* d_ws, size_t ws_size,
                              hipStream_t stream)
{
  (void)in_sizes; (void)n_in; (void)out_size; (void)d_ws; (void)ws_size;
  const float* hs = (const float*)d_in[0];
  // d_in[1] = attention_mask (pure causal) -> analytic
  const float* wq = (const float*)d_in[2];
  const float* wk = (const float*)d_in[3];
  const float* wv = (const float*)d_in[4];
  const float* wo = (const float*)d_in[5];
  const float* cs = (const float*)d_in[6];
  const float* sn = (const float*)d_in[7];
  float* out = (float*)d_out;

  bf16_t *hsb, *wqkvT, *woT, *qkv, *vT, *ao;
  hipGetSymbolAddress((void**)&hsb,   HIP_SYMBOL(g_hsb));
  hipGetSymbolAddress((void**)&wqkvT, HIP_SYMBOL(g_wqkvT));
  hipGetSymbolAddress((void**)&woT,   HIP_SYMBOL(g_woT));
  hipGetSymbolAddress((void**)&qkv,   HIP_SYMBOL(g_qkv));
  hipGetSymbolAddress((void**)&vT,    HIP_SYMBOL(g_vT));
  hipGetSymbolAddress((void**)&ao,    HIP_SYMBOL(g_ao));

  // hidden_states fp32 -> bf16
  cast_f32_bf16<<<(S_LEN * HID) / (256 * 8), 256, 0, stream>>>(hs, hsb);

  // weight transposes (+cast) into fused wqkvT rows [0,4096,5120] and woT
  transpose_f32_bf16<<<dim3(64, 64), 256, 0, stream>>>(wq, wqkvT, HID, HID);
  transpose_f32_bf16<<<dim3(64, 16), 256, 0, stream>>>(
      wk, wqkvT + (size_t)HID * HID, KV_DIM, HID);
  transpose_f32_bf16<<<dim3(64, 16), 256, 0, stream>>>(
      wv, wqkvT + (size_t)(HID + KV_DIM) * HID, KV_DIM, HID);
  transpose_f32_bf16<<<dim3(64, 64), 256, 0, stream>>>(wo, woT, HID, HID);

  // fused QKV projection: [2048,4096] @ [6144,4096]^T -> [2048,6144]
  gemm8p<bf16_t><<<dim3(S_LEN / 128, QKV_DIM / 256), 512, 0, stream>>>(
      hsb, wqkvT, qkv, HID, QKV_DIM);

  // RoPE on q and k (in fused layout)
  rope_kernel<<<(S_LEN * (NH + NKV) * 64) / 256, 256, 0, stream>>>(qkv, cs, sn);

  // v section [s][kvh*128+d] -> vT[kvh][d][s]
  transpose_bf16<<<dim3(S_LEN / 64, HD / 64, NKV), 256, 0, stream>>>(
      qkv + HID + KV_DIM, vT, QKV_DIM, S_LEN, HD, HD * S_LEN);

  // attention (longest blocks first)
  attn_kernel<<<dim3((S_LEN / 64) * NH), 256, 0, stream>>>(qkv, vT, ao);

  // output projection (fp32 out)
  gemm8p<float><<<dim3(S_LEN / 128, HID / 256), 512, 0, stream>>>(
      ao, woT, out, HID, HID);
}

// Round 3
// 589.577 us; speedup vs baseline: 1.0344x; 1.0344x over previous
//
#include <hip/hip_runtime.h>

// ---------------------------------------------------------------------------
// LlamaAttention fwd: B=1, S=2048, HID=4096, NH=32, NKV=8, HD=128, GQA x4.
// fp32 in/out; bf16 MFMA internally.
// R6: GEMM -> m201-style 256x256 8-phase schedule. R5 post-mortem: conflicts
// hit 0 but time flat -> LDS-read-BW-bound (64x64 wave tile = 32 FLOP/LDS-B,
// port needs ~3x the MFMA time). 128x64 wave tiles (2Mx4N, 8 waves) raise
// intensity to 43.7 FLOP/B; 2-buffer LDS (128KiB), 8 phases/iter staging one
// half-tile (2x gl_lds) per phase, counted vmcnt(4) at phases 4/8 only.
// Stage-slot schedule (iteration I consumes tiles 2I,2I+1; bufE=even,bufO=odd):
//   ph0: stage (2I+1).A0  [slot (2I-1).A0 dead since prev ph7]
//   ph1: stage (2I+1).A1
//   ph2: stage (2I+2).B0  [slot (2I).B0 dead since ph0]
//   ph3: stage (2I+2).B1; vmcnt(4) -> confirms (2I+1) fully resident
//   ph4: stage (2I+2).A0  [slot (2I).A0 dead since ph3]
//   ph5: stage (2I+2).A1
//   ph6: stage (2I+3).B0  [slot (2I+1).B0 dead since ph4]
//   ph7: stage (2I+3).B1; vmcnt(4) -> confirms (2I+2) fully resident
// Every overwrite is >=1 end-barrier after the slot's last ds_read; writes
// land only in regions nobody reads during the flight window.
// ---------------------------------------------------------------------------

typedef __bf16 bf16_t;
typedef bf16_t bf16x8_t __attribute__((ext_vector_type(8)));
typedef float f32x4_t __attribute__((ext_vector_type(4)));

#define S_LEN 2048
#define HID 4096
#define NH 32
#define NKV 8
#define HD 128
#define KV_DIM 1024
#define QKV_DIM 6144                 // 4096 q | 1024 k | 1024 v
#define SCALE 0.08838834764831845f   // 1/sqrt(128)

// -------- persistent device scratch ----------------------------------------
__device__ __align__(16) bf16_t g_hsb[(size_t)S_LEN * HID];
__device__ __align__(16) bf16_t g_wqkvT[(size_t)QKV_DIM * HID];  // [n][k]
__device__ __align__(16) bf16_t g_woT[(size_t)HID * HID];        // [n][k]
__device__ __align__(16) bf16_t g_qkv[(size_t)S_LEN * QKV_DIM];  // post-RoPE
__device__ __align__(16) bf16_t g_vT[(size_t)NKV * HD * S_LEN];  // [kvh][d][s]
__device__ __align__(16) bf16_t g_ao[(size_t)S_LEN * HID];       // attn out

// async global->LDS, 16B per lane; LDS dest is wave-uniform base + lane*16
__device__ __forceinline__ void gl_lds16(const bf16_t* g, bf16_t* l) {
  __builtin_amdgcn_global_load_lds(
      (const __attribute__((address_space(1))) void*)g,
      (__attribute__((address_space(3))) void*)l, 16, 0, 0);
}

// ---------------------------------------------------------------------------
__global__ __launch_bounds__(256) void cast_f32_bf16(
    const float* __restrict__ in, bf16_t* __restrict__ out)
{
  size_t i = ((size_t)blockIdx.x * 256 + threadIdx.x) * 8;
  float4 a = *(const float4*)(in + i);
  float4 b = *(const float4*)(in + i + 4);
  bf16x8_t r;
  r[0] = (bf16_t)a.x; r[1] = (bf16_t)a.y; r[2] = (bf16_t)a.z; r[3] = (bf16_t)a.w;
  r[4] = (bf16_t)b.x; r[5] = (bf16_t)b.y; r[6] = (bf16_t)b.z; r[7] = (bf16_t)b.w;
  *(bf16x8_t*)(out + i) = r;
}

// ---------------------------------------------------------------------------
// Transpose+cast: in fp32 [R][C] stride is -> out bf16 [C][R] stride os.
// ---------------------------------------------------------------------------
__global__ __launch_bounds__(256) void transpose_f32_bf16(
    const float* __restrict__ in, bf16_t* __restrict__ out, int is, int os)
{
  __shared__ __align__(16) bf16_t T[64 * 72];
  int r0 = blockIdx.x * 64, c0 = blockIdx.y * 64;
  int t = threadIdx.x;
#pragma unroll
  for (int it = 0; it < 2; ++it) {
    int idx = t + it * 256;
    int r = idx >> 3, c8 = (idx & 7) * 8;
    const float* p = in + (size_t)(r0 + r) * is + c0 + c8;
    float4 a = *(const float4*)p;
    float4 b = *(const float4*)(p + 4);
    bf16x8_t x;
    x[0] = (bf16_t)a.x; x[1] = (bf16_t)a.y; x[2] = (bf16_t)a.z; x[3] = (bf16_t)a.w;
    x[4] = (bf16_t)b.x; x[5] = (bf16_t)b.y; x[6] = (bf16_t)b.z; x[7] = (bf16_t)b.w;
    *(bf16x8_t*)(T + r * 72 + c8) = x;
  }
  __syncthreads();
#pragma unroll
  for (int it = 0; it < 2; ++it) {
    int idx = t + it * 256;
    int c = idx >> 3, r8 = (idx & 7) * 8;
    bf16x8_t x;
#pragma unroll
    for (int i = 0; i < 8; ++i) x[i] = T[(r8 + i) * 72 + c];
    *(bf16x8_t*)(out + (size_t)(c0 + c) * os + r0 + r8) = x;
  }
}

// ---------------------------------------------------------------------------
// bf16 batched transpose (V -> V^T per kv head).
// ---------------------------------------------------------------------------
__global__ __launch_bounds__(256) void transpose_bf16(
    const bf16_t* __restrict__ in, bf16_t* __restrict__ out,
    int is, int os, int in_b, int out_b)
{
  __shared__ __align__(16) bf16_t T[64 * 72];
  const bf16_t* inp = in + (size_t)blockIdx.z * in_b;
  bf16_t* outp = out + (size_t)blockIdx.z * out_b;
  int r0 = blockIdx.x * 64, c0 = blockIdx.y * 64;
  int t = threadIdx.x;
#pragma unroll
  for (int it = 0; it < 2; ++it) {
    int idx = t + it * 256;
    int r = idx >> 3, c8 = (idx & 7) * 8;
    *(bf16x8_t*)(T + r * 72 + c8) =
        *(const bf16x8_t*)(inp + (size_t)(r0 + r) * is + c0 + c8);
  }
  __syncthreads();
#pragma unroll
  for (int it = 0; it < 2; ++it) {
    int idx = t + it * 256;
    int c = idx >> 3, r8 = (idx & 7) * 8;
    bf16x8_t x;
#pragma unroll
    for (int i = 0; i < 8; ++i) x[i] = T[(r8 + i) * 72 + c];
    *(bf16x8_t*)(outp + (size_t)(c0 + c) * os + r0 + r8) = x;
  }
}

// ---------------------------------------------------------------------------
// 256x256 8-phase GEMM: C[M,N] = A[M,K] @ Bt[N,K]^T. BK=64, 512 thr = 8 waves
// (2M x 4N), wave tile 128x64 (8x4 16x16 frags). LDS 128 KiB: 2 buffers x
// {A-half0, A-half1, B-half0, B-half1} x 8192 elem (16 KB). Read swizzle:
// column byte ^= ((row&7)<<4); staging keeps LDS linear and pre-swizzles the
// global source column (involution; verified conflicts==0 in R5).
// ---------------------------------------------------------------------------
#define VM4 asm volatile("s_waitcnt vmcnt(4)" ::: "memory")
#define VM0 asm volatile("s_waitcnt vmcnt(0)" ::: "memory")
#define SCHB __builtin_amdgcn_sched_barrier(0)
#define SBAR __builtin_amdgcn_s_barrier()

#define STAGE_A(tau, h)                                                     \
  { bf16_t* d_ = lds + (((tau) & 1) << 15) + (h) * 8192 + swb;              \
    const bf16_t* g_ = Ags + (size_t)((h) * 128) * K + (tau) * 64;          \
    gl_lds16(g_, d_); gl_lds16(g_ + (size_t)64 * K, d_ + 4096); }
#define STAGE_B(tau, h)                                                     \
  { bf16_t* d_ = lds + (((tau) & 1) << 15) + 16384 + (h) * 8192 + swb;      \
    const bf16_t* g_ = Bgs + (size_t)((h) * 128) * K + (tau) * 64;          \
    gl_lds16(g_, d_); gl_lds16(g_ + (size_t)64 * K, d_ + 4096); }

// One phase: quadrant Q (C-rows 2Q,2Q+1 x all 4 ni, full K=64).
// B frags (bq) loaded once per tile at Q==0, register-resident for Q=1..3.
#define GPHASE(BUF, Q, STAGES, ENDSYNC)                                     \
  {                                                                         \
    if ((Q) == 0) {                                                         \
      _Pragma("unroll")                                                     \
      for (int ni = 0; ni < 4; ++ni) {                                      \
        bq[ni][0] = *(const bf16x8_t*)((BUF) + boff + ni * 2048 + colb0);   \
        bq[ni][1] = *(const bf16x8_t*)((BUF) + boff + ni * 2048 + colb1);   \
      }                                                                     \
    }                                                                       \
    bf16x8_t a00 = *(const bf16x8_t*)((BUF) + aoff + (2*(Q)) * 2048 + colb0);   \
    bf16x8_t a01 = *(const bf16x8_t*)((BUF) + aoff + (2*(Q)) * 2048 + colb1);   \
    bf16x8_t a10 = *(const bf16x8_t*)((BUF) + aoff + (2*(Q)+1) * 2048 + colb0); \
    bf16x8_t a11 = *(const bf16x8_t*)((BUF) + aoff + (2*(Q)+1) * 2048 + colb1); \
    STAGES;                                                                 \
    SBAR;                                                                   \
    asm volatile("s_waitcnt lgkmcnt(0)" ::: "memory");                      \
    SCHB;                                                                   \
    __builtin_amdgcn_s_setprio(1);                                          \
    _Pragma("unroll")                                                       \
    for (int ni = 0; ni < 4; ++ni) {                                        \
      acc[2*(Q)][ni]   = __builtin_amdgcn_mfma_f32_16x16x32_bf16(a00, bq[ni][0], acc[2*(Q)][ni],   0, 0, 0); \
      acc[2*(Q)][ni]   = __builtin_amdgcn_mfma_f32_16x16x32_bf16(a01, bq[ni][1], acc[2*(Q)][ni],   0, 0, 0); \
      acc[2*(Q)+1][ni] = __builtin_amdgcn_mfma_f32_16x16x32_bf16(a10, bq[ni][0], acc[2*(Q)+1][ni], 0, 0, 0); \
      acc[2*(Q)+1][ni] = __builtin_amdgcn_mfma_f32_16x16x32_bf16(a11, bq[ni][1], acc[2*(Q)+1][ni], 0, 0, 0); \
    }                                                                       \
    __builtin_amdgcn_s_setprio(0);                                          \
    ENDSYNC;                                                                \
  }

template <typename CT>
__global__ __launch_bounds__(512, 2) void gemm256(
    const bf16_t* __restrict__ A, const bf16_t* __restrict__ Bt,
    CT* __restrict__ C, int K, int N)
{
  __shared__ __align__(16) bf16_t lds[2 * 32768];   // 128 KiB
  const int t = threadIdx.x;
  const int wid = t >> 6, lane = t & 63;
  const int ln = lane & 15, lq = lane >> 4;
  const int wm = wid >> 2, wn = wid & 3;            // 2 x 4 wave grid
  const int m0 = blockIdx.x * 256, n0 = blockIdx.y * 256;

  // read-side swizzle: column byte ^= ((row&7)<<4); row&7 == ln&7
  const int lx = (ln & 7) << 4;
  const int colb0 = (lq * 16) ^ lx;                 // k-slice 0
  const int colb1 = (64 + lq * 16) ^ lx;            // k-slice 1
  // byte offsets within a 64KB buffer (row stride 128B):
  const int aoff = wm * 16384 + ln * 128;                         // + mi*2048
  const int boff = 32768 + (wn >> 1) * 16384 + ((wn & 1) * 64 + ln) * 128;

  // staging: thread stages 16B of row srow at slot t&7; global col
  // pre-swizzled with the same involution; LDS dest linear.
  const int srow = t >> 3;                                        // 0..63
  const int scol = ((((t & 7) * 16) ^ ((srow & 7) << 4)) >> 1);   // elements
  const int swb = wid * 512;          // wave-uniform elem offset in 8KB chunk
  const bf16_t* Ags = A + (size_t)(m0 + srow) * K + scol;
  const bf16_t* Bgs = Bt + (size_t)(n0 + srow) * K + scol;

  f32x4_t acc[8][4] = {};
  bf16x8_t bq[4][2];
  const char* const bufE = (const char*)lds;            // even tiles
  const char* const bufO = (const char*)lds + 65536;    // odd tiles
  const int NITER = K >> 7;                             // 2 K-tiles / iter

  // prologue: tile0 fully + tile1.B (12 loads); tile1.A staged in iter0 ph0/1
  STAGE_A(0, 0) STAGE_A(0, 1) STAGE_B(0, 0) STAGE_B(0, 1)
  STAGE_B(1, 0) STAGE_B(1, 1)
  VM4;                                  // tile0 resident; tile1.B in flight
  SCHB;
  SBAR;

  for (int I = 0; I < NITER; ++I) {
    const bool stg = (I + 1 < NITER);
    const int tb = 2 * I;
    // ---- tile tb (bufE), phases 0-3 ----
    GPHASE(bufE, 0, STAGE_A(tb + 1, 0), SBAR)
    GPHASE(bufE, 1, STAGE_A(tb + 1, 1), SBAR)
    GPHASE(bufE, 2, if (stg) STAGE_B(tb + 2, 0), SBAR)
    GPHASE(bufE, 3, if (stg) STAGE_B(tb + 2, 1),
           { if (stg) { VM4; } else { VM0; } SCHB; SBAR; })
    // ---- tile tb+1 (bufO), phases 4-7 ----
    GPHASE(bufO, 0, if (stg) STAGE_A(tb + 2, 0), SBAR)
    GPHASE(bufO, 1, if (stg) STAGE_A(tb + 2, 1), SBAR)
    GPHASE(bufO, 2, if (stg) STAGE_B(tb + 3, 0), SBAR)
    GPHASE(bufO, 3, if (stg) STAGE_B(tb + 3, 1),
           { if (stg) { VM4; SCHB; } SBAR; })
  }

  // epilogue (proven C/D mapping: col=ln, row=lq*4+r)
#pragma unroll
  for (int mi = 0; mi < 8; ++mi)
#pragma unroll
    for (int ni = 0; ni < 4; ++ni)
#pragma unroll
      for (int r = 0; r < 4; ++r)
        C[(size_t)(m0 + wm * 128 + mi * 16 + lq * 4 + r) * N
          + n0 + wn * 64 + ni * 16 + ln] = (CT)acc[mi][ni][r];
}

// ---------------------------------------------------------------------------
// RoPE in-place on fused qkv layout [s][6144]; cos/sin fp32 [S][128].
// ---------------------------------------------------------------------------
__global__ __launch_bounds__(256) void rope_kernel(
    bf16_t* __restrict__ qkv, const float* __restrict__ cs,
    const float* __restrict__ sn)
{
  int idx = blockIdx.x * 256 + threadIdx.x;   // S*(NH+NKV)*64 threads exact
  int d = idx & 63;
  int h = (idx >> 6) % (NH + NKV);
  int s = idx / (64 * (NH + NKV));
  float c = cs[s * HD + d], si = sn[s * HD + d];
  bf16_t* base = qkv + (size_t)s * QKV_DIM +
                 ((h < NH) ? h * HD : HID + (h - NH) * HD);
  float x1 = (float)base[d], x2 = (float)base[d + 64];
  base[d]      = (bf16_t)(x1 * c - x2 * si);
  base[d + 64] = (bf16_t)(x2 * c + x1 * si);
}

// ---------------------------------------------------------------------------
// Flash attention, causal, GQA. BK=64 k-tile, 64 q-rows/block (16/wave).
// Longest-first dispatch: qb = 31 - bid/32, head = bid%32.
// ---------------------------------------------------------------------------
__global__ __launch_bounds__(256) void attn_kernel(
    const bf16_t* __restrict__ QKV, const bf16_t* __restrict__ VT,
    bf16_t* __restrict__ O)
{
  __shared__ __align__(16) bf16_t Ks[64 * 136];    // [kpos][d], pad 128->136
  __shared__ __align__(16) bf16_t Vs[128 * 72];    // [d][kpos], pad 64->72
  __shared__ __align__(16) bf16_t Ps[4 * 16 * 72]; // per-wave [16 q][64 k]
  int t = threadIdx.x, wave = t >> 6, lane = t & 63;
  int ln = lane & 15, lq = lane >> 4;
  int bid = blockIdx.x;
  int qb = (S_LEN / 64 - 1) - (bid >> 5);
  int head = bid & 31, kvh = head >> 2;
  int q0 = qb * 64;
  int qr = q0 + wave * 16 + ln;

  bf16x8_t qf[4];
#pragma unroll
  for (int kk = 0; kk < 4; ++kk)
    qf[kk] = *(const bf16x8_t*)(QKV + (size_t)qr * QKV_DIM + head * HD +
                                kk * 32 + lq * 8);

  f32x4_t oa[8] = {};
  float m_r[4] = {-1e30f, -1e30f, -1e30f, -1e30f};
  float l_r[4] = {0.f, 0.f, 0.f, 0.f};

  int krow = t >> 4, kdc = (t & 15) * 8;   // Ks staging: 16 rows/pass
  int vrow = t >> 3, vkc = (t & 7) * 8;    // Vs staging: 32 rows/pass
  const bf16_t* Kg = QKV + HID + (size_t)kvh * HD;
  const bf16_t* Vg = VT + (size_t)kvh * HD * S_LEN;

  for (int kt = 0; kt <= qb; ++kt) {
    int kb = kt * 64;
    __syncthreads();
#pragma unroll
    for (int p = 0; p < 4; ++p) {
      int r_ = p * 16 + krow;
      *(bf16x8_t*)(Ks + r_ * 136 + kdc) =
          *(const bf16x8_t*)(Kg + (size_t)(kb + r_) * QKV_DIM + kdc);
      int d_ = p * 32 + vrow;
      *(bf16x8_t*)(Vs + d_ * 72 + vkc) =
          *(const bf16x8_t*)(Vg + (size_t)d_ * S_LEN + kb + vkc);
    }
    __syncthreads();

    // S = Q @ K^T : 4 col-tiles x 4 k-chunks
    f32x4_t sv[4] = {};
#pragma unroll
    for (int nt = 0; nt < 4; ++nt)
#pragma unroll
      for (int kk = 0; kk < 4; ++kk) {
        bf16x8_t kf = *(const bf16x8_t*)(Ks + (nt * 16 + ln) * 136 +
                                         kk * 32 + lq * 8);
        sv[nt] = __builtin_amdgcn_mfma_f32_16x16x32_bf16(qf[kk], kf, sv[nt],
                                                         0, 0, 0);
      }

    float p_[4][4];                        // [nt][r]
    if (kt == qb) {                        // diagonal tile: mask (uniform br.)
#pragma unroll
      for (int nt = 0; nt < 4; ++nt)
#pragma unroll
        for (int r = 0; r < 4; ++r) {
          int rq = wave * 16 + lq * 4 + r;
          p_[nt][r] = (nt * 16 + ln <= rq) ? sv[nt][r] * SCALE : -1e30f;
        }
    } else {
#pragma unroll
      for (int nt = 0; nt < 4; ++nt)
#pragma unroll
        for (int r = 0; r < 4; ++r) p_[nt][r] = sv[nt][r] * SCALE;
    }

    float mx[4];
#pragma unroll
    for (int r = 0; r < 4; ++r)
      mx[r] = fmaxf(fmaxf(p_[0][r], p_[1][r]), fmaxf(p_[2][r], p_[3][r]));
#pragma unroll
    for (int off = 8; off >= 1; off >>= 1)
#pragma unroll
      for (int r = 0; r < 4; ++r) mx[r] = fmaxf(mx[r], __shfl_xor(mx[r], off, 64));

    float al[4], rs[4];
#pragma unroll
    for (int r = 0; r < 4; ++r) {
      float mn = fmaxf(m_r[r], mx[r]);
      al[r] = __expf(m_r[r] - mn);
      m_r[r] = mn;
      rs[r] = 0.f;
#pragma unroll
      for (int nt = 0; nt < 4; ++nt) {
        p_[nt][r] = __expf(p_[nt][r] - mn);
        rs[r] += p_[nt][r];
      }
    }
#pragma unroll
    for (int off = 8; off >= 1; off >>= 1)
#pragma unroll
      for (int r = 0; r < 4; ++r) rs[r] += __shfl_xor(rs[r], off, 64);
#pragma unroll
    for (int r = 0; r < 4; ++r) l_r[r] = l_r[r] * al[r] + rs[r];
#pragma unroll
    for (int dt = 0; dt < 8; ++dt)
#pragma unroll
      for (int r = 0; r < 4; ++r) oa[dt][r] *= al[r];

    // P: C/D layout -> per-wave LDS slice -> A-operand layout (no barrier)
    bf16_t* myP = Ps + wave * 16 * 72;
#pragma unroll
    for (int nt = 0; nt < 4; ++nt)
#pragma unroll
      for (int r = 0; r < 4; ++r)
        myP[(lq * 4 + r) * 72 + nt * 16 + ln] = (bf16_t)p_[nt][r];
    bf16x8_t pf0 = *(const bf16x8_t*)(myP + ln * 72 + lq * 8);
    bf16x8_t pf1 = *(const bf16x8_t*)(myP + ln * 72 + 32 + lq * 8);
#pragma unroll
    for (int dt = 0; dt < 8; ++dt) {
      bf16x8_t v0 = *(const bf16x8_t*)(Vs + (dt * 16 + ln) * 72 + lq * 8);
      bf16x8_t v1 = *(const bf16x8_t*)(Vs + (dt * 16 + ln) * 72 + 32 + lq * 8);
      oa[dt] = __builtin_amdgcn_mfma_f32_16x16x32_bf16(pf0, v0, oa[dt], 0, 0, 0);
      oa[dt] = __builtin_amdgcn_mfma_f32_16x16x32_bf16(pf1, v1, oa[dt], 0, 0, 0);
    }
  }

#pragma unroll
  for (int dt = 0; dt < 8; ++dt)
#pragma unroll
    for (int r = 0; r < 4; ++r) {
      int row = q0 + wave * 16 + lq * 4 + r;
      O[(size_t)row * HID + head * HD + dt * 16 + ln] =
          (bf16_t)(oa[dt][r] / l_r[r]);
    }
}

// ---------------------------------------------------------------------------
extern "C" void kernel_launch(void* const* d_in, const int* in_sizes, int n_in,
                              void* d_out, int out_size, void* d_ws, size_t ws_size,
                              hipStream_t stream)
{
  (void)in_sizes; (void)n_in; (void)out_size; (void)d_ws; (void)ws_size;
  const float* hs = (const float*)d_in[0];
  // d_in[1] = attention_mask (pure causal) -> analytic
  const float* wq = (const float*)d_in[2];
  const float* wk = (const float*)d_in[3];
  const float* wv = (const float*)d_in[4];
  const float* wo = (const float*)d_in[5];
  const float* cs = (const float*)d_in[6];
  const float* sn = (const float*)d_in[7];
  float* out = (float*)d_out;

  bf16_t *hsb, *wqkvT, *woT, *qkv, *vT, *ao;
  hipGetSymbolAddress((void**)&hsb,   HIP_SYMBOL(g_hsb));
  hipGetSymbolAddress((void**)&wqkvT, HIP_SYMBOL(g_wqkvT));
  hipGetSymbolAddress((void**)&woT,   HIP_SYMBOL(g_woT));
  hipGetSymbolAddress((void**)&qkv,   HIP_SYMBOL(g_qkv));
  hipGetSymbolAddress((void**)&vT,    HIP_SYMBOL(g_vT));
  hipGetSymbolAddress((void**)&ao,    HIP_SYMBOL(g_ao));

  // hidden_states fp32 -> bf16
  cast_f32_bf16<<<(S_LEN * HID) / (256 * 8), 256, 0, stream>>>(hs, hsb);

  // weight transposes (+cast) into fused wqkvT rows [0,4096,5120] and woT
  transpose_f32_bf16<<<dim3(64, 64), 256, 0, stream>>>(wq, wqkvT, HID, HID);
  transpose_f32_bf16<<<dim3(64, 16), 256, 0, stream>>>(
      wk, wqkvT + (size_t)HID * HID, KV_DIM, HID);
  transpose_f32_bf16<<<dim3(64, 16), 256, 0, stream>>>(
      wv, wqkvT + (size_t)(HID + KV_DIM) * HID, KV_DIM, HID);
  transpose_f32_bf16<<<dim3(64, 64), 256, 0, stream>>>(wo, woT, HID, HID);

  // fused QKV projection: [2048,4096] @ [6144,4096]^T -> [2048,6144]
  gemm256<bf16_t><<<dim3(S_LEN / 256, QKV_DIM / 256), 512, 0, stream>>>(
      hsb, wqkvT, qkv, HID, QKV_DIM);

  // RoPE on q and k (in fused layout)
  rope_kernel<<<(S_LEN * (NH + NKV) * 64) / 256, 256, 0, stream>>>(qkv, cs, sn);

  // v section [s][kvh*128+d] -> vT[kvh][d][s]
  transpose_bf16<<<dim3(S_LEN / 64, HD / 64, NKV), 256, 0, stream>>>(
      qkv + HID + KV_DIM, vT, QKV_DIM, S_LEN, HD, HD * S_LEN);

  // attention (longest blocks first)
  attn_kernel<<<dim3((S_LEN / 64) * NH), 256, 0, stream>>>(qkv, vT, ao);

  // output projection (fp32 out)
  gemm256<float><<<dim3(S_LEN / 256, HID / 256), 512, 0, stream>>>(
      ao, woT, out, HID, HID);
}

// Round 4
// 587.764 us; speedup vs baseline: 1.0376x; 1.0031x over previous
//
#include <hip/hip_runtime.h>

// ---------------------------------------------------------------------------
// LlamaAttention fwd: B=1, S=2048, HID=4096, NH=32, NKV=8, HD=128, GQA x4.
// fp32 in/out; bf16 MFMA internally.
// R7: (a) un-serialize gemm256 phases: R6 post-mortem showed forced
// lgkmcnt(0)+sched_barrier(0) before each MFMA cluster serialized
// reads/MFMA/writes (5030 cyc/K-tile vs ~3100 overlapped). Now ds_reads live
// AFTER the phase barrier in the same region as the MFMAs, no manual lgkm
// waits -> compiler emits counted lgkmcnt interleave (its verified strength).
// Barriers/slot schedule/counted vmcnt/swizzle/setprio unchanged.
// (b) fuse cast + 4 weight transposes into one 14336-block prep kernel
// (was 5 serial launches).
// ---------------------------------------------------------------------------

typedef __bf16 bf16_t;
typedef bf16_t bf16x8_t __attribute__((ext_vector_type(8)));
typedef float f32x4_t __attribute__((ext_vector_type(4)));

#define S_LEN 2048
#define HID 4096
#define NH 32
#define NKV 8
#define HD 128
#define KV_DIM 1024
#define QKV_DIM 6144                 // 4096 q | 1024 k | 1024 v
#define SCALE 0.08838834764831845f   // 1/sqrt(128)

// -------- persistent device scratch ----------------------------------------
__device__ __align__(16) bf16_t g_hsb[(size_t)S_LEN * HID];
__device__ __align__(16) bf16_t g_wqkvT[(size_t)QKV_DIM * HID];  // [n][k]
__device__ __align__(16) bf16_t g_woT[(size_t)HID * HID];        // [n][k]
__device__ __align__(16) bf16_t g_qkv[(size_t)S_LEN * QKV_DIM];  // post-RoPE
__device__ __align__(16) bf16_t g_vT[(size_t)NKV * HD * S_LEN];  // [kvh][d][s]
__device__ __align__(16) bf16_t g_ao[(size_t)S_LEN * HID];       // attn out

// async global->LDS, 16B per lane; LDS dest is wave-uniform base + lane*16
__device__ __forceinline__ void gl_lds16(const bf16_t* g, bf16_t* l) {
  __builtin_amdgcn_global_load_lds(
      (const __attribute__((address_space(1))) void*)g,
      (__attribute__((address_space(3))) void*)l, 16, 0, 0);
}

// ---------------------------------------------------------------------------
// Fused prep: one launch replaces {cast hs, transpose wq/wk/wv/wo}.
// Block ranges: [0,4096) cast; [4096,8192) wq; [8192,9216) wk;
// [9216,10240) wv; [10240,14336) wo.
// ---------------------------------------------------------------------------
__device__ __forceinline__ void transpose_body(
    const float* __restrict__ in, bf16_t* __restrict__ out,
    int is, int os, int r0, int c0, int t, bf16_t* T)
{
#pragma unroll
  for (int it = 0; it < 2; ++it) {
    int idx = t + it * 256;
    int r = idx >> 3, c8 = (idx & 7) * 8;
    const float* p = in + (size_t)(r0 + r) * is + c0 + c8;
    float4 a = *(const float4*)p;
    float4 b = *(const float4*)(p + 4);
    bf16x8_t x;
    x[0] = (bf16_t)a.x; x[1] = (bf16_t)a.y; x[2] = (bf16_t)a.z; x[3] = (bf16_t)a.w;
    x[4] = (bf16_t)b.x; x[5] = (bf16_t)b.y; x[6] = (bf16_t)b.z; x[7] = (bf16_t)b.w;
    *(bf16x8_t*)(T + r * 72 + c8) = x;
  }
  __syncthreads();
#pragma unroll
  for (int it = 0; it < 2; ++it) {
    int idx = t + it * 256;
    int c = idx >> 3, r8 = (idx & 7) * 8;
    bf16x8_t x;
#pragma unroll
    for (int i = 0; i < 8; ++i) x[i] = T[(r8 + i) * 72 + c];
    *(bf16x8_t*)(out + (size_t)(c0 + c) * os + r0 + r8) = x;
  }
}

__global__ __launch_bounds__(256) void prep_kernel(
    const float* __restrict__ hs, const float* __restrict__ wq,
    const float* __restrict__ wk, const float* __restrict__ wv,
    const float* __restrict__ wo, bf16_t* __restrict__ hsb,
    bf16_t* __restrict__ wqkvT, bf16_t* __restrict__ woT)
{
  __shared__ __align__(16) bf16_t T[64 * 72];
  int bid = blockIdx.x, t = threadIdx.x;
  if (bid < 4096) {                       // cast hs fp32 -> bf16
    size_t i = ((size_t)bid * 256 + t) * 8;
    float4 a = *(const float4*)(hs + i);
    float4 b = *(const float4*)(hs + i + 4);
    bf16x8_t r;
    r[0] = (bf16_t)a.x; r[1] = (bf16_t)a.y; r[2] = (bf16_t)a.z; r[3] = (bf16_t)a.w;
    r[4] = (bf16_t)b.x; r[5] = (bf16_t)b.y; r[6] = (bf16_t)b.z; r[7] = (bf16_t)b.w;
    *(bf16x8_t*)(hsb + i) = r;
  } else if (bid < 8192) {                // wq [HID][HID] -> wqkvT rows 0..
    int b = bid - 4096;
    transpose_body(wq, wqkvT, HID, HID, (b & 63) * 64, (b >> 6) * 64, t, T);
  } else if (bid < 9216) {                // wk -> wqkvT rows HID..
    int b = bid - 8192;
    transpose_body(wk, wqkvT + (size_t)HID * HID, KV_DIM, HID,
                   (b & 63) * 64, (b >> 6) * 64, t, T);
  } else if (bid < 10240) {               // wv -> wqkvT rows HID+KV_DIM..
    int b = bid - 9216;
    transpose_body(wv, wqkvT + (size_t)(HID + KV_DIM) * HID, KV_DIM, HID,
                   (b & 63) * 64, (b >> 6) * 64, t, T);
  } else {                                // wo -> woT
    int b = bid - 10240;
    transpose_body(wo, woT, HID, HID, (b & 63) * 64, (b >> 6) * 64, t, T);
  }
}

// ---------------------------------------------------------------------------
// bf16 batched transpose (V -> V^T per kv head).
// ---------------------------------------------------------------------------
__global__ __launch_bounds__(256) void transpose_bf16(
    const bf16_t* __restrict__ in, bf16_t* __restrict__ out,
    int is, int os, int in_b, int out_b)
{
  __shared__ __align__(16) bf16_t T[64 * 72];
  const bf16_t* inp = in + (size_t)blockIdx.z * in_b;
  bf16_t* outp = out + (size_t)blockIdx.z * out_b;
  int r0 = blockIdx.x * 64, c0 = blockIdx.y * 64;
  int t = threadIdx.x;
#pragma unroll
  for (int it = 0; it < 2; ++it) {
    int idx = t + it * 256;
    int r = idx >> 3, c8 = (idx & 7) * 8;
    *(bf16x8_t*)(T + r * 72 + c8) =
        *(const bf16x8_t*)(inp + (size_t)(r0 + r) * is + c0 + c8);
  }
  __syncthreads();
#pragma unroll
  for (int it = 0; it < 2; ++it) {
    int idx = t + it * 256;
    int c = idx >> 3, r8 = (idx & 7) * 8;
    bf16x8_t x;
#pragma unroll
    for (int i = 0; i < 8; ++i) x[i] = T[(r8 + i) * 72 + c];
    *(bf16x8_t*)(outp + (size_t)(c0 + c) * os + r0 + r8) = x;
  }
}

// ---------------------------------------------------------------------------
// 256x256 8-phase GEMM: C[M,N] = A[M,K] @ Bt[N,K]^T. BK=64, 512 thr = 8 waves
// (2M x 4N), wave tile 128x64 (8x4 16x16 frags). LDS 128 KiB: 2 buffers x
// {A-half0, A-half1, B-half0, B-half1} x 8192 elem (16 KB).
// Phase = {stage (gl_lds); barrier; ds_reads + 16 MFMA (compiler-scheduled
// counted lgkm interleave); barrier}. Counted vmcnt at phases 4/8 only.
// Read swizzle: column byte ^= ((row&7)<<4); staging keeps LDS linear and
// pre-swizzles the global source column (involution; conflicts==0 measured).
// Stage-slot schedule (iter I consumes tiles 2I,2I+1):
//   ph0: A(2I+1).0  ph1: A(2I+1).1  ph2: B(2I+2).0  ph3: B(2I+2).1 +vmcnt(4)
//   ph4: A(2I+2).0  ph5: A(2I+2).1  ph6: B(2I+3).0  ph7: B(2I+3).1 +vmcnt(4)
// Every slot overwrite is >=1 barrier after its last read.
// ---------------------------------------------------------------------------
#define VM4 asm volatile("s_waitcnt vmcnt(4)" ::: "memory")
#define VM0 asm volatile("s_waitcnt vmcnt(0)" ::: "memory")
#define SCHB __builtin_amdgcn_sched_barrier(0)
#define SBAR __builtin_amdgcn_s_barrier()

#define STAGE_A(tau, h)                                                     \
  { bf16_t* d_ = lds + (((tau) & 1) << 15) + (h) * 8192 + swb;              \
    const bf16_t* g_ = Ags + (size_t)((h) * 128) * K + (tau) * 64;          \
    gl_lds16(g_, d_); gl_lds16(g_ + (size_t)64 * K, d_ + 4096); }
#define STAGE_B(tau, h)                                                     \
  { bf16_t* d_ = lds + (((tau) & 1) << 15) + 16384 + (h) * 8192 + swb;      \
    const bf16_t* g_ = Bgs + (size_t)((h) * 128) * K + (tau) * 64;          \
    gl_lds16(g_, d_); gl_lds16(g_ + (size_t)64 * K, d_ + 4096); }

// One phase: quadrant Q (C-rows 2Q,2Q+1 x all 4 ni, full K=64).
// B frags (bq) loaded once per tile at Q==0, register-resident for Q=1..3.
#define GPHASE(BUF, Q, STAGES, ENDSYNC)                                     \
  {                                                                         \
    STAGES;                                                                 \
    SBAR;                                                                   \
    if ((Q) == 0) {                                                         \
      _Pragma("unroll")                                                     \
      for (int ni = 0; ni < 4; ++ni) {                                      \
        bq[ni][0] = *(const bf16x8_t*)((BUF) + boff + ni * 2048 + colb0);   \
        bq[ni][1] = *(const bf16x8_t*)((BUF) + boff + ni * 2048 + colb1);   \
      }                                                                     \
    }                                                                       \
    bf16x8_t a00 = *(const bf16x8_t*)((BUF) + aoff + (2*(Q)) * 2048 + colb0);   \
    bf16x8_t a01 = *(const bf16x8_t*)((BUF) + aoff + (2*(Q)) * 2048 + colb1);   \
    bf16x8_t a10 = *(const bf16x8_t*)((BUF) + aoff + (2*(Q)+1) * 2048 + colb0); \
    bf16x8_t a11 = *(const bf16x8_t*)((BUF) + aoff + (2*(Q)+1) * 2048 + colb1); \
    __builtin_amdgcn_s_setprio(1);                                          \
    _Pragma("unroll")                                                       \
    for (int ni = 0; ni < 4; ++ni) {                                        \
      acc[2*(Q)][ni]   = __builtin_amdgcn_mfma_f32_16x16x32_bf16(a00, bq[ni][0], acc[2*(Q)][ni],   0, 0, 0); \
      acc[2*(Q)][ni]   = __builtin_amdgcn_mfma_f32_16x16x32_bf16(a01, bq[ni][1], acc[2*(Q)][ni],   0, 0, 0); \
      acc[2*(Q)+1][ni] = __builtin_amdgcn_mfma_f32_16x16x32_bf16(a10, bq[ni][0], acc[2*(Q)+1][ni], 0, 0, 0); \
      acc[2*(Q)+1][ni] = __builtin_amdgcn_mfma_f32_16x16x32_bf16(a11, bq[ni][1], acc[2*(Q)+1][ni], 0, 0, 0); \
    }                                                                       \
    __builtin_amdgcn_s_setprio(0);                                          \
    ENDSYNC;                                                                \
  }

template <typename CT>
__global__ __launch_bounds__(512, 2) void gemm256(
    const bf16_t* __restrict__ A, const bf16_t* __restrict__ Bt,
    CT* __restrict__ C, int K, int N)
{
  __shared__ __align__(16) bf16_t lds[2 * 32768];   // 128 KiB
  const int t = threadIdx.x;
  const int wid = t >> 6, lane = t & 63;
  const int ln = lane & 15, lq = lane >> 4;
  const int wm = wid >> 2, wn = wid & 3;            // 2 x 4 wave grid
  const int m0 = blockIdx.x * 256, n0 = blockIdx.y * 256;

  // read-side swizzle: column byte ^= ((row&7)<<4); row&7 == ln&7
  const int lx = (ln & 7) << 4;
  const int colb0 = (lq * 16) ^ lx;                 // k-slice 0
  const int colb1 = (64 + lq * 16) ^ lx;            // k-slice 1
  // byte offsets within a 64KB buffer (row stride 128B):
  const int aoff = wm * 16384 + ln * 128;                         // + mi*2048
  const int boff = 32768 + (wn >> 1) * 16384 + ((wn & 1) * 64 + ln) * 128;

  // staging: thread stages 16B of row srow at slot t&7; global col
  // pre-swizzled with the same involution; LDS dest linear.
  const int srow = t >> 3;                                        // 0..63
  const int scol = ((((t & 7) * 16) ^ ((srow & 7) << 4)) >> 1);   // elements
  const int swb = wid * 512;          // wave-uniform elem offset in 8KB chunk
  const bf16_t* Ags = A + (size_t)(m0 + srow) * K + scol;
  const bf16_t* Bgs = Bt + (size_t)(n0 + srow) * K + scol;

  f32x4_t acc[8][4] = {};
  bf16x8_t bq[4][2];
  const char* const bufE = (const char*)lds;            // even tiles
  const char* const bufO = (const char*)lds + 65536;    // odd tiles
  const int NITER = K >> 7;                             // 2 K-tiles / iter

  // prologue: tile0 fully + tile1.B (12 loads); tile1.A staged in iter0 ph0/1
  STAGE_A(0, 0) STAGE_A(0, 1) STAGE_B(0, 0) STAGE_B(0, 1)
  STAGE_B(1, 0) STAGE_B(1, 1)
  VM4;                                  // tile0 resident; tile1.B in flight
  SCHB;
  SBAR;

  for (int I = 0; I < NITER; ++I) {
    const bool stg = (I + 1 < NITER);
    const int tb = 2 * I;
    // ---- tile tb (bufE), phases 0-3 ----
    GPHASE(bufE, 0, STAGE_A(tb + 1, 0), SBAR)
    GPHASE(bufE, 1, STAGE_A(tb + 1, 1), SBAR)
    GPHASE(bufE, 2, if (stg) STAGE_B(tb + 2, 0), SBAR)
    GPHASE(bufE, 3, if (stg) STAGE_B(tb + 2, 1),
           { if (stg) { VM4; } else { VM0; } SCHB; SBAR; })
    // ---- tile tb+1 (bufO), phases 4-7 ----
    GPHASE(bufO, 0, if (stg) STAGE_A(tb + 2, 0), SBAR)
    GPHASE(bufO, 1, if (stg) STAGE_A(tb + 2, 1), SBAR)
    GPHASE(bufO, 2, if (stg) STAGE_B(tb + 3, 0), SBAR)
    GPHASE(bufO, 3, if (stg) STAGE_B(tb + 3, 1),
           { if (stg) { VM4; SCHB; } SBAR; })
  }

  // epilogue (proven C/D mapping: col=ln, row=lq*4+r)
#pragma unroll
  for (int mi = 0; mi < 8; ++mi)
#pragma unroll
    for (int ni = 0; ni < 4; ++ni)
#pragma unroll
      for (int r = 0; r < 4; ++r)
        C[(size_t)(m0 + wm * 128 + mi * 16 + lq * 4 + r) * N
          + n0 + wn * 64 + ni * 16 + ln] = (CT)acc[mi][ni][r];
}

// ---------------------------------------------------------------------------
// RoPE in-place on fused qkv layout [s][6144]; cos/sin fp32 [S][128].
// ---------------------------------------------------------------------------
__global__ __launch_bounds__(256) void rope_kernel(
    bf16_t* __restrict__ qkv, const float* __restrict__ cs,
    const float* __restrict__ sn)
{
  int idx = blockIdx.x * 256 + threadIdx.x;   // S*(NH+NKV)*64 threads exact
  int d = idx & 63;
  int h = (idx >> 6) % (NH + NKV);
  int s = idx / (64 * (NH + NKV));
  float c = cs[s * HD + d], si = sn[s * HD + d];
  bf16_t* base = qkv + (size_t)s * QKV_DIM +
                 ((h < NH) ? h * HD : HID + (h - NH) * HD);
  float x1 = (float)base[d], x2 = (float)base[d + 64];
  base[d]      = (bf16_t)(x1 * c - x2 * si);
  base[d + 64] = (bf16_t)(x2 * c + x1 * si);
}

// ---------------------------------------------------------------------------
// Flash attention, causal, GQA. BK=64 k-tile, 64 q-rows/block (16/wave).
// Longest-first dispatch: qb = 31 - bid/32, head = bid%32.
// ---------------------------------------------------------------------------
__global__ __launch_bounds__(256) void attn_kernel(
    const bf16_t* __restrict__ QKV, const bf16_t* __restrict__ VT,
    bf16_t* __restrict__ O)
{
  __shared__ __align__(16) bf16_t Ks[64 * 136];    // [kpos][d], pad 128->136
  __shared__ __align__(16) bf16_t Vs[128 * 72];    // [d][kpos], pad 64->72
  __shared__ __align__(16) bf16_t Ps[4 * 16 * 72]; // per-wave [16 q][64 k]
  int t = threadIdx.x, wave = t >> 6, lane = t & 63;
  int ln = lane & 15, lq = lane >> 4;
  int bid = blockIdx.x;
  int qb = (S_LEN / 64 - 1) - (bid >> 5);
  int head = bid & 31, kvh = head >> 2;
  int q0 = qb * 64;
  int qr = q0 + wave * 16 + ln;

  bf16x8_t qf[4];
#pragma unroll
  for (int kk = 0; kk < 4; ++kk)
    qf[kk] = *(const bf16x8_t*)(QKV + (size_t)qr * QKV_DIM + head * HD +
                                kk * 32 + lq * 8);

  f32x4_t oa[8] = {};
  float m_r[4] = {-1e30f, -1e30f, -1e30f, -1e30f};
  float l_r[4] = {0.f, 0.f, 0.f, 0.f};

  int krow = t >> 4, kdc = (t & 15) * 8;   // Ks staging: 16 rows/pass
  int vrow = t >> 3, vkc = (t & 7) * 8;    // Vs staging: 32 rows/pass
  const bf16_t* Kg = QKV + HID + (size_t)kvh * HD;
  const bf16_t* Vg = VT + (size_t)kvh * HD * S_LEN;

  for (int kt = 0; kt <= qb; ++kt) {
    int kb = kt * 64;
    __syncthreads();
#pragma unroll
    for (int p = 0; p < 4; ++p) {
      int r_ = p * 16 + krow;
      *(bf16x8_t*)(Ks + r_ * 136 + kdc) =
          *(const bf16x8_t*)(Kg + (size_t)(kb + r_) * QKV_DIM + kdc);
      int d_ = p * 32 + vrow;
      *(bf16x8_t*)(Vs + d_ * 72 + vkc) =
          *(const bf16x8_t*)(Vg + (size_t)d_ * S_LEN + kb + vkc);
    }
    __syncthreads();

    // S = Q @ K^T : 4 col-tiles x 4 k-chunks
    f32x4_t sv[4] = {};
#pragma unroll
    for (int nt = 0; nt < 4; ++nt)
#pragma unroll
      for (int kk = 0; kk < 4; ++kk) {
        bf16x8_t kf = *(const bf16x8_t*)(Ks + (nt * 16 + ln) * 136 +
                                         kk * 32 + lq * 8);
        sv[nt] = __builtin_amdgcn_mfma_f32_16x16x32_bf16(qf[kk], kf, sv[nt],
                                                         0, 0, 0);
      }

    float p_[4][4];                        // [nt][r]
    if (kt == qb) {                        // diagonal tile: mask (uniform br.)
#pragma unroll
      for (int nt = 0; nt < 4; ++nt)
#pragma unroll
        for (int r = 0; r < 4; ++r) {
          int rq = wave * 16 + lq * 4 + r;
          p_[nt][r] = (nt * 16 + ln <= rq) ? sv[nt][r] * SCALE : -1e30f;
        }
    } else {
#pragma unroll
      for (int nt = 0; nt < 4; ++nt)
#pragma unroll
        for (int r = 0; r < 4; ++r) p_[nt][r] = sv[nt][r] * SCALE;
    }

    float mx[4];
#pragma unroll
    for (int r = 0; r < 4; ++r)
      mx[r] = fmaxf(fmaxf(p_[0][r], p_[1][r]), fmaxf(p_[2][r], p_[3][r]));
#pragma unroll
    for (int off = 8; off >= 1; off >>= 1)
#pragma unroll
      for (int r = 0; r < 4; ++r) mx[r] = fmaxf(mx[r], __shfl_xor(mx[r], off, 64));

    float al[4], rs[4];
#pragma unroll
    for (int r = 0; r < 4; ++r) {
      float mn = fmaxf(m_r[r], mx[r]);
      al[r] = __expf(m_r[r] - mn);
      m_r[r] = mn;
      rs[r] = 0.f;
#pragma unroll
      for (int nt = 0; nt < 4; ++nt) {
        p_[nt][r] = __expf(p_[nt][r] - mn);
        rs[r] += p_[nt][r];
      }
    }
#pragma unroll
    for (int off = 8; off >= 1; off >>= 1)
#pragma unroll
      for (int r = 0; r < 4; ++r) rs[r] += __shfl_xor(rs[r], off, 64);
#pragma unroll
    for (int r = 0; r < 4; ++r) l_r[r] = l_r[r] * al[r] + rs[r];
#pragma unroll
    for (int dt = 0; dt < 8; ++dt)
#pragma unroll
      for (int r = 0; r < 4; ++r) oa[dt][r] *= al[r];

    // P: C/D layout -> per-wave LDS slice -> A-operand layout (no barrier)
    bf16_t* myP = Ps + wave * 16 * 72;
#pragma unroll
    for (int nt = 0; nt < 4; ++nt)
#pragma unroll
      for (int r = 0; r < 4; ++r)
        myP[(lq * 4 + r) * 72 + nt * 16 + ln] = (bf16_t)p_[nt][r];
    bf16x8_t pf0 = *(const bf16x8_t*)(myP + ln * 72 + lq * 8);
    bf16x8_t pf1 = *(const bf16x8_t*)(myP + ln * 72 + 32 + lq * 8);
#pragma unroll
    for (int dt = 0; dt < 8; ++dt) {
      bf16x8_t v0 = *(const bf16x8_t*)(Vs + (dt * 16 + ln) * 72 + lq * 8);
      bf16x8_t v1 = *(const bf16x8_t*)(Vs + (dt * 16 + ln) * 72 + 32 + lq * 8);
      oa[dt] = __builtin_amdgcn_mfma_f32_16x16x32_bf16(pf0, v0, oa[dt], 0, 0, 0);
      oa[dt] = __builtin_amdgcn_mfma_f32_16x16x32_bf16(pf1, v1, oa[dt], 0, 0, 0);
    }
  }

#pragma unroll
  for (int dt = 0; dt < 8; ++dt)
#pragma unroll
    for (int r = 0; r < 4; ++r) {
      int row = q0 + wave * 16 + lq * 4 + r;
      O[(size_t)row * HID + head * HD + dt * 16 + ln] =
          (bf16_t)(oa[dt][r] / l_r[r]);
    }
}

// ---------------------------------------------------------------------------
extern "C" void kernel_launch(void* const* d_in, const int* in_sizes, int n_in,
                              void* d_out, int out_size, void* d_ws, size_t ws_size,
                              hipStream_t stream)
{
  (void)in_sizes; (void)n_in; (void)out_size; (void)d_ws; (void)ws_size;
  const float* hs = (const float*)d_in[0];
  // d_in[1] = attention_mask (pure causal) -> analytic
  const float* wq = (const float*)d_in[2];
  const float* wk = (const float*)d_in[3];
  const float* wv = (const float*)d_in[4];
  const float* wo = (const float*)d_in[5];
  const float* cs = (const float*)d_in[6];
  const float* sn = (const float*)d_in[7];
  float* out = (float*)d_out;

  bf16_t *hsb, *wqkvT, *woT, *qkv, *vT, *ao;
  hipGetSymbolAddress((void**)&hsb,   HIP_SYMBOL(g_hsb));
  hipGetSymbolAddress((void**)&wqkvT, HIP_SYMBOL(g_wqkvT));
  hipGetSymbolAddress((void**)&woT,   HIP_SYMBOL(g_woT));
  hipGetSymbolAddress((void**)&qkv,   HIP_SYMBOL(g_qkv));
  hipGetSymbolAddress((void**)&vT,    HIP_SYMBOL(g_vT));
  hipGetSymbolAddress((void**)&ao,    HIP_SYMBOL(g_ao));

  // fused prep: cast hs + transpose wq/wk/wv/wo (one launch)
  prep_kernel<<<14336, 256, 0, stream>>>(hs, wq, wk, wv, wo, hsb, wqkvT, woT);

  // fused QKV projection: [2048,4096] @ [6144,4096]^T -> [2048,6144]
  gemm256<bf16_t><<<dim3(S_LEN / 256, QKV_DIM / 256), 512, 0, stream>>>(
      hsb, wqkvT, qkv, HID, QKV_DIM);

  // RoPE on q and k (in fused layout)
  rope_kernel<<<(S_LEN * (NH + NKV) * 64) / 256, 256, 0, stream>>>(qkv, cs, sn);

  // v section [s][kvh*128+d] -> vT[kvh][d][s]
  transpose_bf16<<<dim3(S_LEN / 64, HD / 64, NKV), 256, 0, stream>>>(
      qkv + HID + KV_DIM, vT, QKV_DIM, S_LEN, HD, HD * S_LEN);

  // attention (longest blocks first)
  attn_kernel<<<dim3((S_LEN / 64) * NH), 256, 0, stream>>>(qkv, vT, ao);

  // output projection (fp32 out)
  gemm256<float><<<dim3(S_LEN / 256, HID / 256), 512, 0, stream>>>(
      ao, woT, out, HID, HID);
}